// Round 3
// baseline (1262.004 us; speedup 1.0000x reference)
//
#include <hip/hip_runtime.h>
#include <math.h>

// Problem constants
constexpr int NTOK = 16384;   // B*L
constexpr int HD   = 2048;    // H
constexpr int ID   = 5504;    // I  (= 86*64 = 172*32)
#define EPS_RMS 1e-6f

typedef unsigned short u16;
typedef unsigned int   u32;
typedef short bf16x8 __attribute__((ext_vector_type(8)));
typedef float f32x4  __attribute__((ext_vector_type(4)));

// ---- workspace layout (bytes) ----
// hdr: [0]=active-token counter, [1]=mask-dtype flag (1 = byte mask)
#define OFS_MAP   1024u
#define OFS_H     (1u<<20)
#define OFS_GW    (OFS_H  + 67108864u)   // h: 16384*2048*2
#define OFS_UW    (OFS_GW + 22544384u)   // each wT: 5504*2048*2
#define OFS_DW    (OFS_UW + 22544384u)
#define OFS_P     (OFS_DW + 22544384u)   // p: 16384*5504*2 -> total ~316 MB

__device__ __forceinline__ u16 f2bf(float f) {
  u32 u = __float_as_uint(f);
  u += 0x7fffu + ((u >> 16) & 1u);      // round-to-nearest-even
  return (u16)(u >> 16);
}

__device__ __forceinline__ void gload_lds16(const u16* g, u16* l) {
  // async global->LDS, 16B/lane; LDS dest = wave-uniform base + lane*16
  __builtin_amdgcn_global_load_lds((const __attribute__((address_space(1))) u32*)g,
                                   (__attribute__((address_space(3))) u32*)l, 16, 0, 0);
}

// ---- kernel 0: detect mask dtype (bool-bytes vs int32) + init counter ----
__global__ void init_detect(const u32* __restrict__ mw, int* __restrict__ hdr) {
  __shared__ int s_any;
  if (threadIdx.x == 0) s_any = 0;
  __syncthreads();
  int any = 0;
  // first 16KB is in-bounds for both interpretations (16384 bytes vs 64KB)
  for (int i = threadIdx.x; i < 4096; i += 256) any |= (mw[i] > 1u) ? 1 : 0;
  if (any) atomicOr(&s_any, 1);
  __syncthreads();
  if (threadIdx.x == 0) { hdr[0] = 0; hdr[1] = s_any; }
}

// ---- kernel 1: zero d_out (masked tokens must be exactly 0) and h (tile pad) ----
__global__ void zero_bufs(float4* __restrict__ out4, uint4* __restrict__ h4) {
  const size_t n_out = (size_t)NTOK * HD / 4;       // float4 count
  const size_t n_h   = (size_t)NTOK * HD * 2 / 16;  // 16B chunks
  size_t i = (size_t)blockIdx.x * blockDim.x + threadIdx.x;
  size_t stride = (size_t)gridDim.x * blockDim.x;
  float4 zf = {0.f, 0.f, 0.f, 0.f};
  uint4  zu = {0u, 0u, 0u, 0u};
  for (size_t k = i; k < n_out; k += stride) out4[k] = zf;
  for (size_t k = i; k < n_h;   k += stride) h4[k]  = zu;
}

// ---- kernel 2: tiled transpose f32[R][C] -> bf16[C][R] (K-contiguous weights) ----
__global__ __launch_bounds__(256) void transpose_f32_bf16(
    const float* __restrict__ in, u16* __restrict__ out, int R, int C) {
  __shared__ float t[64][65];                  // +1 pad: conflict-free
  const int c0 = blockIdx.x * 64, r0 = blockIdx.y * 64;
  const int tid = threadIdx.x, tx = tid & 63, ty = tid >> 6;
#pragma unroll
  for (int i = 0; i < 16; ++i) {
    int r = ty + i * 4;
    t[r][tx] = in[(size_t)(r0 + r) * C + c0 + tx];
  }
  __syncthreads();
#pragma unroll
  for (int i = 0; i < 16; ++i) {
    int cc = ty + i * 4;
    out[(size_t)(c0 + cc) * R + r0 + tx] = f2bf(t[tx][cc]);
  }
}

// ---- kernel 3: RMSNorm + bf16 cast + compaction ----
__global__ __launch_bounds__(256) void rmsnorm_compact(
    const float* __restrict__ x, const void* __restrict__ mask,
    const float* __restrict__ lnw, u16* __restrict__ h,
    int* __restrict__ hdr, int* __restrict__ map) {
  const int token = blockIdx.x;
  int keep;
  if (hdr[1]) keep = ((const unsigned char*)mask)[token] != 0;
  else        keep = ((const int*)mask)[token] != 0;
  if (!keep) return;
  __shared__ int s_slot;
  __shared__ float s_ws[4];
  const int tid = threadIdx.x;
  if (tid == 0) s_slot = atomicAdd(&hdr[0], 1);
  const float4* xr = (const float4*)(x + (size_t)token * HD);
  float4 a = xr[tid], b = xr[tid + 256];
  float s = a.x*a.x + a.y*a.y + a.z*a.z + a.w*a.w
          + b.x*b.x + b.y*b.y + b.z*b.z + b.w*b.w;
#pragma unroll
  for (int off = 32; off; off >>= 1) s += __shfl_xor(s, off, 64);
  if ((tid & 63) == 0) s_ws[tid >> 6] = s;
  __syncthreads();
  const float tot = s_ws[0] + s_ws[1] + s_ws[2] + s_ws[3];
  const float sc = rsqrtf(tot * (1.0f / HD) + EPS_RMS);
  const int slot = s_slot;
  const float4* lw = (const float4*)lnw;
  float4 w0 = lw[tid], w1 = lw[tid + 256];
  u16* hr = h + (size_t)slot * HD;
  ushort4 o0, o1;
  o0.x = f2bf(a.x * sc * w0.x); o0.y = f2bf(a.y * sc * w0.y);
  o0.z = f2bf(a.z * sc * w0.z); o0.w = f2bf(a.w * sc * w0.w);
  o1.x = f2bf(b.x * sc * w1.x); o1.y = f2bf(b.y * sc * w1.y);
  o1.z = f2bf(b.z * sc * w1.z); o1.w = f2bf(b.w * sc * w1.w);
  ((ushort4*)hr)[tid]       = o0;
  ((ushort4*)hr)[tid + 256] = o1;
  if (tid == 0) map[slot] = token;
}

// ---- kernel 4: GEMM1 + fused GLU. A=h[M,2048], B1/B2=wT[5504,2048]; tile 128x64 dual-acc ----
__global__ __launch_bounds__(256) void gemm1_glu(
    const u16* __restrict__ h, const u16* __restrict__ gwT, const u16* __restrict__ uwT,
    const float* __restrict__ gate_b, const float* __restrict__ up_b,
    u16* __restrict__ p, const int* __restrict__ hdr) {
  const int nact = hdr[0];
  const int npad = (nact + 127) & ~127;
  const int m0 = blockIdx.y * 128;
  if (m0 >= npad) return;
  const int n0 = blockIdx.x * 64;

  __shared__ u16 As[2][128 * 32];
  __shared__ u16 Gs[2][64 * 32];
  __shared__ u16 Us[2][64 * 32];

  const int tid = threadIdx.x, w = tid >> 6, l = tid & 63;
  const int wm = w >> 1, wn = w & 1;
  const int srow = l >> 2, skb = (l & 3) * 8;

  const u16* gA = h   + (size_t)(m0 + w * 32 + srow) * HD + skb;
  const u16* gG = gwT + (size_t)(n0 + w * 16 + srow) * HD + skb;
  const u16* gU = uwT + (size_t)(n0 + w * 16 + srow) * HD + skb;

#define STAGE1(b, kk) do {                                    \
    gload_lds16(gA + (kk),            &As[b][(w * 32) * 32]); \
    gload_lds16(gA + 16 * HD + (kk),  &As[b][(w * 32 + 16) * 32]); \
    gload_lds16(gG + (kk),            &Gs[b][(w * 16) * 32]); \
    gload_lds16(gU + (kk),            &Us[b][(w * 16) * 32]); \
  } while (0)

  f32x4 zero4 = {0.f, 0.f, 0.f, 0.f};
  f32x4 ag[4][2], au[4][2];
#pragma unroll
  for (int m = 0; m < 4; ++m)
#pragma unroll
    for (int n = 0; n < 2; ++n) { ag[m][n] = zero4; au[m][n] = zero4; }

  STAGE1(0, 0);
  __syncthreads();
  const int la = l & 15, kg = (l >> 4) * 8;
  const int NK = HD / 32;
  for (int ki = 0; ki < NK; ++ki) {
    const int b = ki & 1;
    if (ki + 1 < NK) STAGE1(b ^ 1, (ki + 1) * 32);  // overlap with compute(cur)
    bf16x8 af[4], gf[2], uf[2];
#pragma unroll
    for (int m = 0; m < 4; ++m)
      af[m] = *(const bf16x8*)&As[b][(wm * 64 + m * 16 + la) * 32 + kg];
#pragma unroll
    for (int n = 0; n < 2; ++n) {
      gf[n] = *(const bf16x8*)&Gs[b][(wn * 32 + n * 16 + la) * 32 + kg];
      uf[n] = *(const bf16x8*)&Us[b][(wn * 32 + n * 16 + la) * 32 + kg];
    }
#pragma unroll
    for (int m = 0; m < 4; ++m)
#pragma unroll
      for (int n = 0; n < 2; ++n) {
        ag[m][n] = __builtin_amdgcn_mfma_f32_16x16x32_bf16(af[m], gf[n], ag[m][n], 0, 0, 0);
        au[m][n] = __builtin_amdgcn_mfma_f32_16x16x32_bf16(af[m], uf[n], au[m][n], 0, 0, 0);
      }
    __syncthreads();  // drains next-stage vmcnt AFTER MFMA (T3-minimum)
  }
#undef STAGE1
  // epilogue: p = silu(g + gb) * (u + ub), bf16
#pragma unroll
  for (int m = 0; m < 4; ++m)
#pragma unroll
    for (int n = 0; n < 2; ++n) {
      const int col = n0 + wn * 32 + n * 16 + la;
      const float gb = gate_b[col], ub = up_b[col];
      const int rbase = m0 + wm * 64 + m * 16 + (l >> 4) * 4;
#pragma unroll
      for (int j = 0; j < 4; ++j) {
        float g = ag[m][n][j] + gb;
        float u = au[m][n][j] + ub;
        float sg = g / (1.0f + __expf(-g));
        p[(size_t)(rbase + j) * ID + col] = f2bf(sg * u);
      }
    }
}

// ---- kernel 5: GEMM2 down-proj + bias + scatter. A=p[M,5504], B=dwT[2048,5504]; tile 128x128 ----
__global__ __launch_bounds__(256) void gemm2_down(
    const u16* __restrict__ p, const u16* __restrict__ dwT,
    const float* __restrict__ down_b, float* __restrict__ out,
    const int* __restrict__ hdr, const int* __restrict__ map) {
  const int nact = hdr[0];
  const int npad = (nact + 127) & ~127;
  const int m0 = blockIdx.y * 128;
  if (m0 >= npad) return;
  const int n0 = blockIdx.x * 128;

  __shared__ u16 As[2][128 * 32];
  __shared__ u16 Bs[2][128 * 32];

  const int tid = threadIdx.x, w = tid >> 6, l = tid & 63;
  const int wm = w >> 1, wn = w & 1;
  const int srow = l >> 2, skb = (l & 3) * 8;

  const u16* gA = p   + (size_t)(m0 + w * 32 + srow) * ID + skb;
  const u16* gB = dwT + (size_t)(n0 + w * 32 + srow) * ID + skb;

#define STAGE2(b, kk) do {                                    \
    gload_lds16(gA + (kk),           &As[b][(w * 32) * 32]);  \
    gload_lds16(gA + 16 * ID + (kk), &As[b][(w * 32 + 16) * 32]); \
    gload_lds16(gB + (kk),           &Bs[b][(w * 32) * 32]);  \
    gload_lds16(gB + 16 * ID + (kk), &Bs[b][(w * 32 + 16) * 32]); \
  } while (0)

  f32x4 zero4 = {0.f, 0.f, 0.f, 0.f};
  f32x4 acc[4][4];
#pragma unroll
  for (int m = 0; m < 4; ++m)
#pragma unroll
    for (int n = 0; n < 4; ++n) acc[m][n] = zero4;

  STAGE2(0, 0);
  __syncthreads();
  const int la = l & 15, kg = (l >> 4) * 8;
  const int NK = ID / 32;  // 172
  for (int ki = 0; ki < NK; ++ki) {
    const int b = ki & 1;
    if (ki + 1 < NK) STAGE2(b ^ 1, (ki + 1) * 32);
    bf16x8 af[4], bf[4];
#pragma unroll
    for (int m = 0; m < 4; ++m)
      af[m] = *(const bf16x8*)&As[b][(wm * 64 + m * 16 + la) * 32 + kg];
#pragma unroll
    for (int n = 0; n < 4; ++n)
      bf[n] = *(const bf16x8*)&Bs[b][(wn * 64 + n * 16 + la) * 32 + kg];
#pragma unroll
    for (int m = 0; m < 4; ++m)
#pragma unroll
      for (int n = 0; n < 4; ++n)
        acc[m][n] = __builtin_amdgcn_mfma_f32_16x16x32_bf16(af[m], bf[n], acc[m][n], 0, 0, 0);
    __syncthreads();
  }
#undef STAGE2
  // epilogue: scatter rows back to token order, + down_b (masked rows untouched = 0)
#pragma unroll
  for (int m = 0; m < 4; ++m)
#pragma unroll
    for (int n = 0; n < 4; ++n) {
      const int col = n0 + wn * 64 + n * 16 + la;
      const float db = down_b[col];
      const int rbase = m0 + wm * 64 + m * 16 + (l >> 4) * 4;
#pragma unroll
      for (int j = 0; j < 4; ++j) {
        const int slot = rbase + j;
        if (slot < nact) {
          const int tok = map[slot];
          out[(size_t)tok * HD + col] = acc[m][n][j] + db;
        }
      }
    }
}

extern "C" void kernel_launch(void* const* d_in, const int* in_sizes, int n_in,
                              void* d_out, int out_size, void* d_ws, size_t ws_size,
                              hipStream_t stream) {
  const float* x      = (const float*)d_in[0];
  const void*  mask   = d_in[1];
  const float* ln_w   = (const float*)d_in[2];
  const float* gate_w = (const float*)d_in[3];
  const float* gate_b = (const float*)d_in[4];
  const float* up_w   = (const float*)d_in[5];
  const float* up_b   = (const float*)d_in[6];
  const float* down_w = (const float*)d_in[7];
  const float* down_b = (const float*)d_in[8];
  float* out = (float*)d_out;

  char* ws = (char*)d_ws;
  int* hdr = (int*)ws;
  int* map = (int*)(ws + OFS_MAP);
  u16* h   = (u16*)(ws + OFS_H);
  u16* gwT = (u16*)(ws + OFS_GW);
  u16* uwT = (u16*)(ws + OFS_UW);
  u16* dwT = (u16*)(ws + OFS_DW);
  u16* p   = (u16*)(ws + OFS_P);

  init_detect<<<1, 256, 0, stream>>>((const u32*)mask, hdr);
  zero_bufs<<<2048, 256, 0, stream>>>((float4*)out, (uint4*)h);
  transpose_f32_bf16<<<dim3(ID / 64, HD / 64), 256, 0, stream>>>(gate_w, gwT, HD, ID);
  transpose_f32_bf16<<<dim3(ID / 64, HD / 64), 256, 0, stream>>>(up_w, uwT, HD, ID);
  transpose_f32_bf16<<<dim3(HD / 64, ID / 64), 256, 0, stream>>>(down_w, dwT, ID, HD);
  rmsnorm_compact<<<NTOK, 256, 0, stream>>>(x, mask, ln_w, h, hdr, map);
  gemm1_glu<<<dim3(ID / 64, NTOK / 128), 256, 0, stream>>>(h, gwT, uwT, gate_b, up_b, p, hdr);
  gemm2_down<<<dim3(HD / 128, NTOK / 128), 256, 0, stream>>>(p, dwT, down_b, out, hdr, map);
}